// Round 8
// baseline (176.552 us; speedup 1.0000x reference)
//
#include <hip/hip_runtime.h>
#include <limits.h>

typedef __attribute__((ext_vector_type(8))) short short8v;
typedef __attribute__((ext_vector_type(4))) float f32x4;

#define W_  128
#define HW_ 16384

#define MFMA32(a, b, c) __builtin_amdgcn_mfma_f32_16x16x32_bf16(a, b, c, 0, 0, 0)

__device__ __forceinline__ short bf16b(float f) {
    unsigned u = __float_as_uint(f);
    u += 0x7fffu + ((u >> 16) & 1u);   // RNE
    return (short)(u >> 16);
}
__device__ __forceinline__ unsigned bf16pk(float lo, float hi) {
    unsigned ul = __float_as_uint(lo);
    ul += 0x7fffu + ((ul >> 16) & 1u);
    unsigned uh = __float_as_uint(hi);
    uh += 0x7fffu + ((uh >> 16) & 1u);
    return (ul >> 16) | (uh & 0xffff0000u);
}

// 1024 threads = 16 waves; tile 16h x 16w, all 81 displacements.
// Wave wid owns ONE output row (h0+wid): acc[9][2] = 72 regs -> <=128/wave
// (enforced by __launch_bounds__(1024)) -> 4 waves/SIMD, 2x prior concurrency.
// Single 48KB in2 buffer [r24][j4][col32][8k bf16] with per-(r,j) dword
// rotation ROT=((r*4+j)&7)*4 (mod 128) to spread staging-write banks 8->~24.
// Junk cols 24..31 are never written and feed only never-read acc elements,
// so stale/wrapped garbage there is harmless (no zero-init needed).
// 2 barriers per K-chunk (stage | compute); staging loads for t+1 issue after
// MFMA so the barrier's vmcnt drain covers their latency.
// Epilogue: ONE barrier pair; 84KB ldso (aliases buffer) holds all 81 bands.
// NOTE: all acc[][] indices compile-time constant (round-3 lesson: runtime
// index -> scratch demotion -> 1.37GB spill writes).
__global__ __launch_bounds__(1024)
void corr_kernel(const float* __restrict__ in1, const float* __restrict__ in2,
                 float* __restrict__ out)
{
    __shared__ __attribute__((aligned(16))) unsigned char smem[84992];
    short*    lds  = (short*)smem;      // staging view (48KB used)
    unsigned* ldsI = (unsigned*)smem;   // dword view for packed writes
    float*    ldso = (float*)smem;      // epilogue view (81*260*4 = 84240B)

    const int tid  = threadIdx.x;
    const int lane = tid & 63;
    const int wid  = tid >> 6;        // 0..15 = output row within tile
    const int m    = lane & 15;       // M row / N col in 16x16 tile
    const int g    = lane >> 4;       // k-octet 0..3

    int bid = blockIdx.x;
    int swz = (bid & 7) * 64 + (bid >> 3);       // bijective XCD swizzle; 1 image/XCD
    int n   = swz >> 6;
    int h0  = ((swz >> 3) & 7) << 4;
    int w0  = (swz & 7) << 4;

    const float* in1n = in1 + (size_t)n * (256 * HW_);
    const float* in2n = in2 + (size_t)n * (256 * HW_);

    // ---- staging geometry: pair-unit u = (r*16+kp)*6+q, 2304 units ----
    // unit: row r(0..23), k-pair kp (j=kp>>2, kp3=kp&3 -> channels 8j+2kp3{,+1}),
    // cols 4q..4q+3. Writes 4 rotated dwords; reads un-rotate identically.
    int gof0[3], wbas[3], wrot[3];
    bool act[3];
#pragma unroll
    for (int s = 0; s < 3; ++s) {
        int u    = tid + s * 1024;
        act[s]   = (u < 2304);
        int q    = u % 6;
        int rest = u / 6;
        int kp   = rest & 15;
        int r    = rest >> 4;         // 0..23
        int row  = h0 - 4 + r;
        int col0 = w0 - 4 + 4 * q;
        bool inb = act[s] && ((unsigned)row < 128u) && ((unsigned)col0 < 125u);
        int  cc  = 8 * (kp >> 2) + 2 * (kp & 3);
        gof0[s]  = inb ? (cc * HW_ + row * W_ + col0) : INT_MIN;
        int rj   = r * 4 + (kp >> 2);
        wbas[s]  = rj * 128;
        wrot[s]  = 16 * q + (kp & 3) + ((rj & 7) << 2);
    }
    const int abase = (8 * g) * HW_ + (h0 + wid) * W_ + (w0 + m);

    f32x4 acc[9][2];
#pragma unroll
    for (int d = 0; d < 9; ++d)
#pragma unroll
        for (int t = 0; t < 2; ++t)
            acc[d][t] = (f32x4){0.f, 0.f, 0.f, 0.f};

    // ---- prologue: loads for chunk 0 (in2 + A) ----
    f32x4 sf[3][2];
    float af[8];
#pragma unroll
    for (int s = 0; s < 3; ++s)
#pragma unroll
        for (int e = 0; e < 2; ++e) {
            f32x4 v = (f32x4){0.f, 0.f, 0.f, 0.f};
            if (gof0[s] != INT_MIN) v = *(const f32x4*)(in2n + gof0[s] + e * HW_);
            sf[s][e] = v;
        }
#pragma unroll
    for (int i = 0; i < 8; ++i) af[i] = in1n[abase + i * HW_];

    // ---- main loop: 8 chunks of 32 channels; 2 barriers per chunk ----
#pragma unroll 1
    for (int t = 0; t < 8; ++t) {
        // stage chunk t (rotated pair-packed dword writes)
#pragma unroll
        for (int s = 0; s < 3; ++s)
            if (act[s]) {
#pragma unroll
                for (int d = 0; d < 4; ++d)
                    ldsI[wbas[s] + ((wrot[s] + 4 * d) & 127)] =
                        bf16pk(sf[s][0][d], sf[s][1][d]);
            }
        __syncthreads();
        __builtin_amdgcn_sched_barrier(0);

        // A frags for chunk t (loaded during previous compute phase)
        short8v a8;
#pragma unroll
        for (int i = 0; i < 8; ++i) a8[i] = bf16b(af[i]);
        // issue A loads for chunk t+1 (overlap with MFMA)
        if (t < 7) {
            const int koff = (t + 1) * 32 * HW_;
#pragma unroll
            for (int i = 0; i < 8; ++i) af[i] = in1n[abase + koff + i * HW_];
        }

        // MFMA: wave wid, dy -> in2 LDS row r = wid+dy (rotated b128 reads)
#pragma unroll
        for (int dy = 0; dy < 9; ++dy) {
            int rj   = (wid + dy) * 4 + g;
            int base = rj * 128;
            int rot  = (rj & 7) << 2;
#pragma unroll
            for (int nt = 0; nt < 2; ++nt) {
                int dw = base + ((((nt * 16 + m) << 2) + rot) & 127);
                short8v b = *(const short8v*)&lds[dw * 2];
                acc[dy][nt] = MFMA32(a8, b, acc[dy][nt]);
            }
        }

        // issue in2 loads for chunk t+1; barrier's vmcnt drain covers latency
        if (t < 7) {
            const int koff = (t + 1) * 32 * HW_;
#pragma unroll
            for (int s = 0; s < 3; ++s)
#pragma unroll
                for (int e = 0; e < 2; ++e) {
                    f32x4 v = (f32x4){0.f, 0.f, 0.f, 0.f};
                    if (gof0[s] != INT_MIN) v = *(const f32x4*)(in2n + gof0[s] + e * HW_ + koff);
                    sf[s][e] = v;
                }
        }
        __syncthreads();
        __builtin_amdgcn_sched_barrier(0);
    }

    // ---- epilogue: ONE barrier pair; all 81 bands -> ldso -> coalesced stores ----
    // (loop's closing barrier already separates last MFMA reads from ldso writes)
#pragma unroll
    for (int dy = 0; dy < 9; ++dy) {
#pragma unroll
        for (int nt = 0; nt < 2; ++nt) {
#pragma unroll
            for (int i = 0; i < 4; ++i) {
                int mm = 4 * g + i;              // D row = pixel w offset
                int dx = nt * 16 + m - mm;       // D col = mm + dx
                if (dx >= 0 && dx < 9)
                    ldso[(dy * 9 + dx) * 260 + wid * 16 + mm] = acc[dy][nt][i];
            }
        }
    }
    __syncthreads();
    __builtin_amdgcn_sched_barrier(0);
    const size_t outb = (size_t)n * 81 * HW_;
#pragma unroll
    for (int e = 0; e < 21; ++e) {
        int t2 = tid + e * 1024;
        if (t2 < 20736) {
            int dydx = t2 >> 8;                  // dy*9+dx
            int rem  = t2 & 255;                 // row*16 + w
            out[outb + (size_t)dydx * HW_ +
                (size_t)(h0 + (rem >> 4)) * W_ + (w0 + (rem & 15))] = ldso[dydx * 260 + rem];
        }
    }
}

extern "C" void kernel_launch(void* const* d_in, const int* in_sizes, int n_in,
                              void* d_out, int out_size, void* d_ws, size_t ws_size,
                              hipStream_t stream) {
    const float* in1 = (const float*)d_in[0];
    const float* in2 = (const float*)d_in[1];
    float* out = (float*)d_out;
    corr_kernel<<<dim3(512), dim3(1024), 0, stream>>>(in1, in2, out);
}